// Round 4
// baseline (141.022 us; speedup 1.0000x reference)
//
#include <hip/hip_runtime.h>

// Problem constants
#define B_     64
#define L_     1024
#define D_     1280   // 320 float4
#define H1_    640
#define H2_    320
#define NSPLIT 32     // per-batch stripes for pooling (dense part layout)
#define KS_    16     // k-splits for mlp1 inside fused kernel
#define KC_    80     // 1280/16
#define NJT_   10     // j-tiles of 64 cols
#define NBLK2_ (NJT_ * KS_)   // 160 blocks in fused kernel

// ---------------- Kernel 1: per-batch even-split stripe partial sums ----------------
// grid (NSPLIT, B_), 320 threads. Dense output part[b][s][d/4] — no tags.
// 2048 blocks -> ~6 resident blocks/CU (30 waves) + unroll 8 => deep MLP.
__global__ void pool_partial(const float* __restrict__ rep, const int* __restrict__ blen,
                             float* __restrict__ part) {
    const int s   = blockIdx.x;     // stripe
    const int b   = blockIdx.y;     // batch
    const int tid = threadIdx.x;    // 0..319 (float4 lane)
    const int n   = blen[b] - 2;    // valid rows (>=1)

    const int l0 = 1 + (s * n) / NSPLIT;
    const int l1 = 1 + ((s + 1) * n) / NSPLIT;

    float4 acc = make_float4(0.f, 0.f, 0.f, 0.f);
    const float4* base = (const float4*)rep + (size_t)b * L_ * (D_ / 4) + tid;
    #pragma unroll 8
    for (int l = l0; l < l1; ++l) {
        float4 v = base[(size_t)l * (D_ / 4)];
        acc.x += v.x; acc.y += v.y; acc.z += v.z; acc.w += v.w;
    }
    ((float4*)part)[((size_t)b * NSPLIT + s) * (D_ / 4) + tid] = acc;
}

// ---------------- Kernel 2: fused stripe-reduce + MLP1 + barrier + MLP23 ----------------
// 160 blocks x 256 threads. Phase 1 (all blocks): block (jt,ks) gathers its
// pooled k-slice from part (sum 32 stripes, /n), stages in LDS, computes the
// W1 partial product into hpart. Device-atomic barrier. Phase 2 (blocks 0..63):
// per-batch h-reduce + relu, emb = relu(h@W2+b2) -> out, y = emb@W3+b3 -> out.
__global__ void fused_mlp(const float* __restrict__ part, const int* __restrict__ blen,
                          const float* __restrict__ W1, const float* __restrict__ b1,
                          const float* __restrict__ W2, const float* __restrict__ b2,
                          const float* __restrict__ W3, const float* __restrict__ b3,
                          float* __restrict__ hpart, unsigned int* __restrict__ ctr,
                          float* __restrict__ out) {
    const int bid = blockIdx.x;
    const int tid = threadIdx.x;        // 0..255
    const int jt  = bid % NJT_;         // 0..9
    const int ks  = bid / NJT_;         // 0..15
    const int k0  = ks * KC_;
    const int j0  = jt * 64;
    const int jl  = tid & 63;
    const int b0  = (tid >> 6) * 16;

    __shared__ float pl[B_][KC_];       // pooled k-slice [b][kk]  (20 KB)
    __shared__ float invn[B_];

    if (tid < B_) {
        int n = blen[tid] - 2; if (n < 1) n = 1;
        invn[tid] = 1.0f / (float)n;
    }
    __syncthreads();

    // ---- gather: pl[b][kk] = (sum_s part[b][s][k0+kk]) * invn[b] ----
    // thread handles 5 (b, kk4) slots; 32-stripe sum each, float4 wide.
    for (int e = tid; e < B_ * (KC_ / 4); e += 256) {
        const int b   = e / (KC_ / 4);
        const int kk4 = e % (KC_ / 4);
        const float4* p = (const float4*)part + ((size_t)b * NSPLIT) * (D_ / 4) + (k0 / 4) + kk4;
        float4 acc = make_float4(0.f, 0.f, 0.f, 0.f);
        #pragma unroll 8
        for (int s = 0; s < NSPLIT; ++s) {
            float4 v = p[(size_t)s * (D_ / 4)];
            acc.x += v.x; acc.y += v.y; acc.z += v.z; acc.w += v.w;
        }
        const float iv = invn[b];
        *(float4*)&pl[b][kk4 * 4] = make_float4(acc.x * iv, acc.y * iv, acc.z * iv, acc.w * iv);
    }
    __syncthreads();

    // ---- mlp1 partial: thread owns 16 batches x 1 column (j0+jl) ----
    float acc[16];
    #pragma unroll
    for (int r = 0; r < 16; ++r) acc[r] = 0.f;

    const float* w1p = W1 + (size_t)k0 * H1_ + j0 + jl;
    for (int kk = 0; kk < KC_; kk += 4) {
        const float w0 = w1p[(size_t)(kk + 0) * H1_];
        const float w1 = w1p[(size_t)(kk + 1) * H1_];
        const float w2 = w1p[(size_t)(kk + 2) * H1_];
        const float w3 = w1p[(size_t)(kk + 3) * H1_];
        #pragma unroll
        for (int r = 0; r < 16; ++r) {
            float4 p = *(const float4*)&pl[b0 + r][kk];
            acc[r] = fmaf(p.x, w0, acc[r]);
            acc[r] = fmaf(p.y, w1, acc[r]);
            acc[r] = fmaf(p.z, w2, acc[r]);
            acc[r] = fmaf(p.w, w3, acc[r]);
        }
    }
    float* hp = hpart + (size_t)ks * B_ * H1_;
    #pragma unroll
    for (int r = 0; r < 16; ++r)
        hp[(size_t)(b0 + r) * H1_ + j0 + jl] = acc[r];

    // ---- device-scope barrier: all 160 blocks' hpart visible ----
    __threadfence();                 // make my global writes device-visible
    __syncthreads();                 // all threads fenced before tid0 arrives
    if (tid == 0) atomicAdd(ctr, 1u);
    if (bid >= B_) return;           // blocks 64..159 done

    if (tid == 0) {
        while (atomicAdd(ctr, 0u) < (unsigned)NBLK2_)
            __builtin_amdgcn_s_sleep(2);
    }
    __syncthreads();
    __threadfence();

    // ---- mlp23 for batch b = bid ----
    const int b = bid;
    __shared__ float hrow[H1_];
    __shared__ float erow[H2_];

    // h[b][j] = relu(sum_ks hpart + b1), j strided by 256
    for (int j = tid; j < H1_; j += 256) {
        float s = b1[j];
        #pragma unroll
        for (int k = 0; k < KS_; ++k)
            s += hpart[((size_t)k * B_ + b) * H1_ + j];
        hrow[j] = fmaxf(s, 0.f);
    }
    __syncthreads();

    // emb[b][j] = relu(hrow . W2[:,j] + b2[j]); 320 cols on 256 threads
    for (int j = tid; j < H2_; j += 256) {
        float s0 = 0.f, s1 = 0.f, s2 = 0.f, s3 = 0.f;
        #pragma unroll 2
        for (int k = 0; k < H1_; k += 4) {
            s0 = fmaf(hrow[k + 0], W2[(size_t)(k + 0) * H2_ + j], s0);
            s1 = fmaf(hrow[k + 1], W2[(size_t)(k + 1) * H2_ + j], s1);
            s2 = fmaf(hrow[k + 2], W2[(size_t)(k + 2) * H2_ + j], s2);
            s3 = fmaf(hrow[k + 3], W2[(size_t)(k + 3) * H2_ + j], s3);
        }
        float s = fmaxf(b2[j] + ((s0 + s1) + (s2 + s3)), 0.f);
        erow[j] = s;
        out[128 + (size_t)b * H2_ + j] = s;
    }
    __syncthreads();

    // y[b][o] = erow . W3[:,o] + b3[o]  (two waves, shuffle reduce)
    if (tid < 128) {
        const int o = tid >> 6, lane = tid & 63;
        float s = 0.f;
        for (int j = lane; j < H2_; j += 64)
            s = fmaf(erow[j], W3[(size_t)j * 2 + o], s);
        #pragma unroll
        for (int off = 32; off >= 1; off >>= 1)
            s += __shfl_down(s, off, 64);
        if (lane == 0) out[(size_t)b * 2 + o] = s + b3[o];
    }
}

extern "C" void kernel_launch(void* const* d_in, const int* in_sizes, int n_in,
                              void* d_out, int out_size, void* d_ws, size_t ws_size,
                              hipStream_t stream) {
    const float* rep  = (const float*)d_in[0];
    const int*   blen = (const int*)  d_in[1];
    const float* W1   = (const float*)d_in[2];
    const float* b1   = (const float*)d_in[3];
    const float* W2   = (const float*)d_in[4];
    const float* b2   = (const float*)d_in[5];
    const float* W3   = (const float*)d_in[6];
    const float* b3   = (const float*)d_in[7];
    float* out = (float*)d_out;

    // workspace layout (floats):
    //   part   B_*NSPLIT*D_   = 2,621,440  (10.5 MB)
    //   hpart  KS_*B_*H1_    =   655,360  (2.6 MB)
    //   ctr    1 uint
    float*        ws    = (float*)d_ws;
    float*        part  = ws;
    float*        hpart = part + (size_t)B_ * NSPLIT * D_;
    unsigned int* ctr   = (unsigned int*)(hpart + (size_t)KS_ * B_ * H1_);

    hipMemsetAsync(ctr, 0, sizeof(unsigned int), stream);   // reset barrier ctr (graph-safe)
    pool_partial<<<dim3(NSPLIT, B_), 320, 0, stream>>>(rep, blen, part);
    fused_mlp<<<NBLK2_, 256, 0, stream>>>(part, blen, W1, b1, W2, b2, W3, b3,
                                          hpart, ctr, out);
}

// Round 5
// 83.834 us; speedup vs baseline: 1.6822x; 1.6822x over previous
//
#include <hip/hip_runtime.h>

// Problem constants
#define B_     64
#define L_     1024
#define D_     1280   // 320 float4
#define H1_    640
#define H2_    320
#define NSPLIT 16     // per-batch stripes for pooling
#define KS_    16     // k-splits for mlp1
#define KC_    80     // 1280/16
#define NJT_   10     // j-tiles of 64 cols

// ---------------- Kernel 1: per-batch even-split stripe partial sums ----------------
// grid (NSPLIT, B_), 320 threads. part[b][s][d] layout (stripe stride 5 KB).
// Identical work/coalescing to the R2 best (77.5us).
__global__ void pool_partial(const float* __restrict__ rep, const int* __restrict__ blen,
                             float* __restrict__ part) {
    const int s   = blockIdx.x;     // stripe
    const int b   = blockIdx.y;     // batch
    const int tid = threadIdx.x;    // 0..319 (float4 lane)
    const int n   = blen[b] - 2;    // valid rows (>=1)

    const int l0 = 1 + (s * n) / NSPLIT;
    const int l1 = 1 + ((s + 1) * n) / NSPLIT;

    float4 acc = make_float4(0.f, 0.f, 0.f, 0.f);
    const float4* base = (const float4*)rep + (size_t)b * L_ * (D_ / 4) + tid;
    #pragma unroll 4
    for (int l = l0; l < l1; ++l) {
        float4 v = base[(size_t)l * (D_ / 4)];
        acc.x += v.x; acc.y += v.y; acc.z += v.z; acc.w += v.w;
    }
    // always write (empty stripes contribute zeros)
    ((float4*)part)[((size_t)b * NSPLIT + s) * (D_ / 4) + tid] = acc;
}

// ---------------- Kernel 2: fused stripe-reduce + mlp1 partial ----------------
// grid (NJT_, KS_) = 160 blocks, 256 threads. Block (jt,ks) sums the 16 stripes
// of its k-slice from part (L2/L3-served), scales by 1/n into LDS, then computes
// the W1 partial product. W1 read exactly once grid-wide. No pooled round-trip.
__global__ void reduce_mlp1(const float* __restrict__ part, const int* __restrict__ blen,
                            const float* __restrict__ W1, float* __restrict__ hpart) {
    const int jt  = blockIdx.x;     // 0..9
    const int ks  = blockIdx.y;     // 0..15
    const int tid = threadIdx.x;    // 0..255
    const int jl  = tid & 63;
    const int b0  = (tid >> 6) * 16;
    const int k0  = ks * KC_;
    const int j0  = jt * 64;

    __shared__ float pl[B_][KC_];   // pooled k-slice [b][kk]  (20 KB)
    __shared__ float invn[B_];

    if (tid < B_) {
        int n = blen[tid] - 2; if (n < 1) n = 1;
        invn[tid] = 1.0f / (float)n;
    }
    __syncthreads();

    // gather: pl[b][kk4*4..+3] = invn[b] * sum_s part[b][s][k0+kk4*4..]
    // 1280 float4 slots / 256 threads = 5 slots each, 16 strided loads per slot.
    for (int e = tid; e < B_ * (KC_ / 4); e += 256) {
        const int b   = e / (KC_ / 4);
        const int kk4 = e % (KC_ / 4);
        const float4* p = (const float4*)part + (size_t)b * NSPLIT * (D_ / 4) + (k0 / 4) + kk4;
        float4 acc = make_float4(0.f, 0.f, 0.f, 0.f);
        #pragma unroll
        for (int s = 0; s < NSPLIT; ++s) {
            float4 v = p[(size_t)s * (D_ / 4)];
            acc.x += v.x; acc.y += v.y; acc.z += v.z; acc.w += v.w;
        }
        const float iv = invn[b];
        *(float4*)&pl[b][kk4 * 4] = make_float4(acc.x * iv, acc.y * iv, acc.z * iv, acc.w * iv);
    }
    __syncthreads();

    // mlp1 partial: thread owns 16 batches x 1 column (j0+jl)
    float acc[16];
    #pragma unroll
    for (int r = 0; r < 16; ++r) acc[r] = 0.f;

    const float* w1p = W1 + (size_t)k0 * H1_ + j0 + jl;
    for (int kk = 0; kk < KC_; kk += 4) {
        const float w0 = w1p[(size_t)(kk + 0) * H1_];
        const float w1 = w1p[(size_t)(kk + 1) * H1_];
        const float w2 = w1p[(size_t)(kk + 2) * H1_];
        const float w3 = w1p[(size_t)(kk + 3) * H1_];
        #pragma unroll
        for (int r = 0; r < 16; ++r) {
            float4 p = *(const float4*)&pl[b0 + r][kk];
            acc[r] = fmaf(p.x, w0, acc[r]);
            acc[r] = fmaf(p.y, w1, acc[r]);
            acc[r] = fmaf(p.z, w2, acc[r]);
            acc[r] = fmaf(p.w, w3, acc[r]);
        }
    }

    float* hp = hpart + (size_t)ks * B_ * H1_;
    #pragma unroll
    for (int r = 0; r < 16; ++r)
        hp[(size_t)(b0 + r) * H1_ + j0 + jl] = acc[r];
}

// ---------------- Kernel 3: h reduce + relu, emb, y ----------------
// block per batch, 320 threads.
__global__ void mlp23(const float* __restrict__ hpart, const float* __restrict__ b1,
                      const float* __restrict__ W2, const float* __restrict__ b2,
                      const float* __restrict__ W3, const float* __restrict__ b3,
                      float* __restrict__ out) {
    const int b   = blockIdx.x;
    const int tid = threadIdx.x;   // 0..319
    __shared__ float hrow[H1_];
    __shared__ float erow[H2_];

    // phase 1: h[b][j] = relu(sum_ks hpart + b1)
    for (int j = tid; j < H1_; j += 320) {
        float s = b1[j];
        #pragma unroll
        for (int ks = 0; ks < KS_; ++ks)
            s += hpart[((size_t)ks * B_ + b) * H1_ + j];
        hrow[j] = fmaxf(s, 0.f);
    }
    __syncthreads();

    // phase 2: emb[b][j] = relu(hrow . W2[:,j] + b2[j]) — 4 accumulators
    {
        const int j = tid;
        float s0 = 0.f, s1 = 0.f, s2 = 0.f, s3 = 0.f;
        #pragma unroll 2
        for (int k = 0; k < H1_; k += 4) {
            s0 = fmaf(hrow[k + 0], W2[(size_t)(k + 0) * H2_ + j], s0);
            s1 = fmaf(hrow[k + 1], W2[(size_t)(k + 1) * H2_ + j], s1);
            s2 = fmaf(hrow[k + 2], W2[(size_t)(k + 2) * H2_ + j], s2);
            s3 = fmaf(hrow[k + 3], W2[(size_t)(k + 3) * H2_ + j], s3);
        }
        float s = fmaxf(b2[j] + ((s0 + s1) + (s2 + s3)), 0.f);
        erow[j] = s;
        out[128 + (size_t)b * H2_ + j] = s;
    }
    __syncthreads();

    // phase 3: y[b][o] = erow . W3[:,o] + b3[o]  (two waves, shuffle reduce)
    if (tid < 128) {
        const int o = tid >> 6, lane = tid & 63;
        float s = 0.f;
        for (int j = lane; j < H2_; j += 64)
            s = fmaf(erow[j], W3[(size_t)j * 2 + o], s);
        #pragma unroll
        for (int off = 32; off >= 1; off >>= 1)
            s += __shfl_down(s, off, 64);
        if (lane == 0) out[(size_t)b * 2 + o] = s + b3[o];
    }
}

extern "C" void kernel_launch(void* const* d_in, const int* in_sizes, int n_in,
                              void* d_out, int out_size, void* d_ws, size_t ws_size,
                              hipStream_t stream) {
    const float* rep  = (const float*)d_in[0];
    const int*   blen = (const int*)  d_in[1];
    const float* W1   = (const float*)d_in[2];
    const float* b1   = (const float*)d_in[3];
    const float* W2   = (const float*)d_in[4];
    const float* b2   = (const float*)d_in[5];
    const float* W3   = (const float*)d_in[6];
    const float* b3   = (const float*)d_in[7];
    float* out = (float*)d_out;

    // workspace layout (floats):
    //   part   B_*NSPLIT*D_ = 1,310,720  (5.24 MB)
    //   hpart  KS_*B_*H1_   =   655,360  (2.62 MB)
    float* ws    = (float*)d_ws;
    float* part  = ws;
    float* hpart = part + (size_t)B_ * NSPLIT * D_;

    pool_partial<<<dim3(NSPLIT, B_), 320, 0, stream>>>(rep, blen, part);
    reduce_mlp1 <<<dim3(NJT_, KS_), 256, 0, stream>>>(part, blen, W1, hpart);
    mlp23       <<<B_, 320, 0, stream>>>(hpart, b1, W2, b2, W3, b3, out);
}